// Round 8
// baseline (1309.782 us; speedup 1.0000x reference)
//
#include <hip/hip_runtime.h>
#include <hip/hip_bf16.h>
#include <stdint.h>

typedef __attribute__((ext_vector_type(8))) short short8;
typedef __attribute__((ext_vector_type(16))) float f32x16;

#define AS1 __attribute__((address_space(1)))
#define AS3 __attribute__((address_space(3)))

// RNE float->bf16 (inputs are finite; no NaN handling needed)
static __device__ __forceinline__ unsigned short f2bf(float f) {
    unsigned int u = __float_as_uint(f);
    u += 0x7FFFu + ((u >> 16) & 1u);
    return (unsigned short)(u >> 16);
}

__global__ void init_amax(unsigned int* amax) {
    if (threadIdx.x < 2) amax[threadIdx.x] = 0u;
}

__global__ void absmax_kernel(const float4* __restrict__ w, size_t n4,
                              unsigned int* __restrict__ out) {
    float m = 0.0f;
    size_t i = (size_t)blockIdx.x * blockDim.x + threadIdx.x;
    size_t stride = (size_t)gridDim.x * blockDim.x;
    for (; i < n4; i += stride) {
        float4 v = w[i];
        m = fmaxf(m, fmaxf(fmaxf(fabsf(v.x), fabsf(v.y)),
                           fmaxf(fabsf(v.z), fabsf(v.w))));
    }
    #pragma unroll
    for (int off = 32; off > 0; off >>= 1)
        m = fmaxf(m, __shfl_down(m, off, 64));
    __shared__ float sm[4];
    int lane = threadIdx.x & 63, wid = threadIdx.x >> 6;
    if (lane == 0) sm[wid] = m;
    __syncthreads();
    if (threadIdx.x == 0) {
        float bm = fmaxf(fmaxf(sm[0], sm[1]), fmaxf(sm[2], sm[3]));
        atomicMax(out, __float_as_uint(bm));  // floats >=0: uint bit-compare monotone
    }
}

// FP4 E2M1 quantize to exact bf16 grid value (scale kept separate).
// idx = sum(a > mids[j]) matches np.searchsorted(mids, a, side='left').
static __device__ __forceinline__ unsigned short quant_one(float wv, float scale) {
    float a = fabsf(wv) / scale;
    int idx = (a > 0.25f) + (a > 0.75f) + (a > 1.25f) + (a > 1.75f)
            + (a > 2.5f)  + (a > 3.5f)  + (a > 5.0f);
    const unsigned long long lo = 0x3FC03F803F000000ull;  // bf16 bits {0,.5,1,1.5}
    const unsigned long long hi = 0x40C0408040404000ull;  // bf16 bits {2,3,4,6}
    unsigned long long tab = (idx < 4) ? lo : hi;
    unsigned short mag = (unsigned short)(tab >> ((idx & 3) * 16));
    unsigned short sgn = (unsigned short)((__float_as_uint(wv) >> 16) & 0x8000u);
    return (unsigned short)(mag | sgn);
}

__global__ void quant_kernel(const float4* __restrict__ w, size_t n4,
                             const unsigned int* __restrict__ amax,
                             ushort4* __restrict__ q) {
    const float scale = __uint_as_float(*amax) / 6.0f;
    size_t i = (size_t)blockIdx.x * blockDim.x + threadIdx.x;
    size_t stride = (size_t)gridDim.x * blockDim.x;
    for (; i < n4; i += stride) {
        float4 v = w[i];
        ushort4 o;
        o.x = quant_one(v.x, scale);
        o.y = quant_one(v.y, scale);
        o.z = quant_one(v.z, scale);
        o.w = quant_one(v.w, scale);
        q[i] = o;
    }
}

__global__ void cast_bf16_kernel(const float4* __restrict__ x, size_t n4,
                                 ushort4* __restrict__ o) {
    size_t i = (size_t)blockIdx.x * blockDim.x + threadIdx.x;
    size_t stride = (size_t)gridDim.x * blockDim.x;
    for (; i < n4; i += stride) {
        float4 v = x[i];
        ushort4 r;
        r.x = f2bf(v.x); r.y = f2bf(v.y); r.z = f2bf(v.z); r.w = f2bf(v.w);
        o[i] = r;
    }
}

// ========= 256x256 GEMM, BK=64, mfma_32x32x16 (R6 skeleton, shape swap) =========
// C[M][N] = A[M][K] (bf16) * B[N][K]^T (bf16), f32 acc.
// 512 thr = 8 waves (2M x 4N), per-wave 128x64 = 4mb x 2nb blocks of 32x32,
// K-tile = 64 = 4 ksteps of 16. LDS 128KiB, buf by tile parity; per buf:
// A0@0 A1@16K B0@32K B1@48K. Subtile = 16 rows x 32 k (1024B);
// byte = s*1024 + swz(rin*64 + kin*2), swz(x)=x^(((x>>9)&1)<<5).
// global_load_lds dest LINEAR; global source carries inverse swizzle.
//
// ds_read for 32-row operand (mb,ks): lane l reads row mb*32+(l&31),
// k = ks*16+(l>>5)*8: addr = base + mb*4096 + sp32[ks],
// sp32[ks] = ((l>>4)&1)*2048 + (ks>>1)*1024
//          + (((l&15)*64 + (ks&1)*32 + ((l>>5)&1)*16) ^ (((l>>3)&1)<<5)).
// B identical with col = wn*64 + nb*32 + (l&31), base = lds+32768+wn*8192.
//
// Per K-tile: issue all 24 reads (aP 8, b0 4, b1 4, aQ 8); stage 2 A-halves
// of tile T+1 -> other buf; lgkm(12) -> 16 MFMA ks01; lgkm(0); BAR;
// stage 2 B-halves of tile T+2 -> own buf; 16 MFMA ks23; vmcnt(4); BAR.
// vmcnt ledger (induction): enter tile with 4 outstanding (T+1.B0B1);
// +4 (T+1.A0A1) +4 (T+2.B0B1); vmcnt(4) retires T+1's 8. Tail: vmcnt(0).

#define GLL(gp, dst)                                                    \
    __builtin_amdgcn_global_load_lds((const AS1 unsigned int*)(gp),     \
        (AS3 unsigned int*)(dst), 16, 0, 0)

#define STG(gp, ldsoff)                                       \
    do {                                                      \
        GLL((gp) + goff0, lds + (ldsoff) + tid * 16);         \
        GLL((gp) + goff1, lds + (ldsoff) + 8192 + tid * 16);  \
    } while (0)

// 8 ds_read_b128: dst[mb*2+kk] = A operand (mb, ksbase+kk)
#define LDA8(dst, base, ksbase)                                               \
    do {                                                                      \
        _Pragma("unroll") for (int _m = 0; _m < 4; ++_m)                      \
            _Pragma("unroll") for (int _k = 0; _k < 2; ++_k)                  \
                dst[_m * 2 + _k] = *(const short8*)((base) + _m * 4096 +      \
                                                    sp32[(ksbase) + _k]);     \
    } while (0)

// 4 ds_read_b128: dst[nb*2+kk] = B operand (nb, ksbase+kk)
#define LDB4(dst, base, ksbase)                                               \
    do {                                                                      \
        _Pragma("unroll") for (int _n = 0; _n < 2; ++_n)                      \
            _Pragma("unroll") for (int _k = 0; _k < 2; ++_k)                  \
                dst[_n * 2 + _k] = *(const short8*)((base) + _n * 4096 +      \
                                                    sp32[(ksbase) + _k]);     \
    } while (0)

// 16 MFMA (4mb x 2nb x 2kk) on one k-half
#define MFK(ARR, BRR)                                                          \
    do {                                                                       \
        _Pragma("unroll") for (int _m = 0; _m < 4; ++_m)                       \
            _Pragma("unroll") for (int _n = 0; _n < 2; ++_n)                   \
                _Pragma("unroll") for (int _k = 0; _k < 2; ++_k)               \
                    acc[_m][_n] = __builtin_amdgcn_mfma_f32_32x32x16_bf16(     \
                        ARR[_m * 2 + _k], BRR[_n * 2 + _k], acc[_m][_n],       \
                        0, 0, 0);                                              \
    } while (0)

#define BAR()  __builtin_amdgcn_s_barrier()
#define PRIO(x) __builtin_amdgcn_s_setprio(x)
#define SCHB() __builtin_amdgcn_sched_barrier(0)
#define LGKM(n) do { SCHB(); asm volatile("s_waitcnt lgkmcnt(" #n ")"); SCHB(); } while (0)

// One K-tile. VMODE: 2 = vmcnt(4), 1 = vmcnt(0), 0 = none.
#define KTILE32(ldsB_, ldsA_, MA, kA, oA0_, oA1_, MB, kB, oB0_, oB1_, VMODE)   \
    do {                                                                       \
        LDA8(aP, ldsA_, 0);            /* A mb0-3, ks0-1: 8 reads */           \
        LDB4(b0, ldsB_, 0);            /* B nb0-1, ks0-1: 4 */                 \
        if (MA) { STG(pA0 + (kA), oA0_); STG(pA1 + (kA), oA1_); }              \
        LDB4(b1, ldsB_, 2);            /* B ks2-3: 4 */                        \
        LDA8(aQ, ldsA_, 2);            /* A ks2-3: 8 */                        \
        LGKM(12);                      /* aP+b0 ready; b1,aQ in flight */      \
        PRIO(1); MFK(aP, b0); PRIO(0);                                         \
        LGKM(0);                       /* all 24 reads done -> buf free */     \
        BAR();                                                                 \
        if (MB) { STG(pB0 + (kB), oB0_); STG(pB1 + (kB), oB1_); }              \
        SCHB();                                                                \
        PRIO(1); MFK(aQ, b1); PRIO(0);                                         \
        if (VMODE == 2) { asm volatile("s_waitcnt vmcnt(4)"); }                \
        if (VMODE == 1) { asm volatile("s_waitcnt vmcnt(0)"); }                \
        BAR();                                                                 \
    } while (0)

template <int RELU_BF16>
__global__ __launch_bounds__(512, 2)
void gemm8(const unsigned short* __restrict__ A,
           const unsigned short* __restrict__ B,
           const float* __restrict__ bias,
           const unsigned int* __restrict__ amax,
           float* __restrict__ outF,
           unsigned short* __restrict__ outH,
           int M, int N, int K, int gx) {
    __shared__ __align__(16) char lds[131072];

    const int tid  = threadIdx.x;
    const int lane = tid & 63;
    const int wid  = tid >> 6;
    const int wm   = wid >> 2;   // 0..1: 128-row half
    const int wn   = wid & 3;    // 0..3: 64-col slice

    // XCD-aware swizzle (nwg % 8 == 0 for both our grids -> bijective)
    const int nwg = gridDim.x;
    const int wg  = blockIdx.x;
    const int swz = (wg & 7) * (nwg >> 3) + (wg >> 3);
    const int bx  = swz % gx;
    const int by  = swz / gx;
    const int col0 = bx * 256;
    const int row0 = by * 256;

    // per-lane swizzled ds_read byte offsets for the 4 ksteps (32-row operands)
    int sp32[4];
    {
        const int l = lane;
        const int base16 = ((l >> 4) & 1) * 2048;
        const int inner0 = ((l & 15) << 6) + (((l >> 5) & 1) << 4);
        const int flip = ((l >> 3) & 1) << 5;
        #pragma unroll
        for (int ks = 0; ks < 4; ++ks)
            sp32[ks] = base16 + (ks >> 1) * 1024 +
                       ((inner0 + ((ks & 1) << 5)) ^ flip);
    }

    const char* ldsA_E = lds + wm * 16384;
    const char* ldsB_E = lds + 32768 + wn * 8192;
    const char* ldsA_O = ldsA_E + 65536;
    const char* ldsB_O = ldsB_E + 65536;

    // stage source map: linear LDS off o = l*8192 + tid*16 holds element
    // (row,k) = unswz(o); precompute element offsets row*K + k.
    int goff0, goff1;
    {
        int o = tid * 16;
        int s = o >> 10, b = o & 1023;
        b ^= ((b >> 9) & 1) << 5;
        goff0 = (((s >> 1) << 4) + (b >> 6)) * K + ((s & 1) << 5) + ((b & 63) >> 1);
        o = 8192 + tid * 16;
        s = o >> 10; b = o & 1023;
        b ^= ((b >> 9) & 1) << 5;
        goff1 = (((s >> 1) << 4) + (b >> 6)) * K + ((s & 1) << 5) + ((b & 63) >> 1);
    }
    const unsigned short* pA0 = A + (size_t)row0 * K;
    const unsigned short* pA1 = A + (size_t)(row0 + 128) * K;
    const unsigned short* pB0 = B + (size_t)col0 * K;
    const unsigned short* pB1 = B + (size_t)(col0 + 128) * K;

    // prologue: tile0 all 4 halves -> E; tile1 B0,B1 -> O
    STG(pB0, 32768); STG(pB1, 49152); STG(pA0, 0); STG(pA1, 16384);
    STG(pB0 + 64, 98304); STG(pB1 + 64, 114688);
    asm volatile("s_waitcnt vmcnt(4)");   // tile0's 8 loads landed
    BAR();

    f32x16 acc[4][2] = {};
    short8 aP[8], aQ[8], b0[4], b1[4];
    const int NIT2 = K >> 7;   // pairs of K-tiles

    for (int it = 0; it < NIT2 - 1; ++it) {
        const int o0 = it * 128;
        // tile 2it (E): stage (2it+1).A0A1 -> O, (2it+2).B0B1 -> E
        KTILE32(ldsB_E, ldsA_E, 1, o0 + 64, 65536, 81920,
                1, o0 + 128, 32768, 49152, 2);
        // tile 2it+1 (O): stage (2it+2).A0A1 -> E, (2it+3).B0B1 -> O
        KTILE32(ldsB_O, ldsA_O, 1, o0 + 128, 0, 16384,
                1, o0 + 192, 98304, 114688, 2);
    }
    {
        const int o0 = (NIT2 - 1) * 128;   // peeled tail pair
        KTILE32(ldsB_E, ldsA_E, 1, o0 + 64, 65536, 81920,
                0, 0, 0, 0, 1);            // drain: vmcnt(0)
        KTILE32(ldsB_O, ldsA_O, 0, 0, 0, 0,
                0, 0, 0, 0, 0);            // nothing outstanding
    }

    // epilogue: 32x32 C/D layout (m74/m101): col = lane&31,
    // row = (reg&3) + 8*(reg>>2) + 4*(lane>>5)
    const float scale = __uint_as_float(*amax) / 6.0f;
    #pragma unroll
    for (int nb = 0; nb < 2; ++nb) {
        const int col = col0 + wn * 64 + nb * 32 + (lane & 31);
        const float bvv = bias[col];
        #pragma unroll
        for (int mb = 0; mb < 4; ++mb) {
            const int rbase = row0 + wm * 128 + mb * 32 + ((lane >> 5) & 1) * 4;
            #pragma unroll
            for (int r = 0; r < 16; ++r) {
                const int row = rbase + (r & 3) + 8 * (r >> 2);
                float v = acc[mb][nb][r] * scale + bvv;
                if (RELU_BF16) {
                    v = fmaxf(v, 0.0f);
                    outH[(size_t)row * N + col] = f2bf(v);
                } else {
                    outF[(size_t)row * N + col] = v;
                }
            }
        }
    }
}

extern "C" void kernel_launch(void* const* d_in, const int* in_sizes, int n_in,
                              void* d_out, int out_size, void* d_ws, size_t ws_size,
                              hipStream_t stream) {
    const float* x  = (const float*)d_in[0];   // [8192, 2048]
    const float* W1 = (const float*)d_in[1];   // [8192, 2048]
    const float* b1 = (const float*)d_in[2];   // [8192]
    const float* W2 = (const float*)d_in[3];   // [2048, 8192]
    const float* b2 = (const float*)d_in[4];   // [2048]
    float* out = (float*)d_out;                // [8192, 2048] f32

    const int Bm = 8192, Din = 2048, Dh = 8192, Dout = 2048;
    const size_t nW1 = (size_t)Dh * Din;
    const size_t nW2 = (size_t)Dout * Dh;
    const size_t nX  = (size_t)Bm * Din;
    const size_t nH  = (size_t)Bm * Dh;

    const size_t need = 256 + 2 * (nW1 + nW2 + nX + nH);
    if (ws_size < need) return;

    uint8_t* ws = (uint8_t*)d_ws;
    unsigned int*   amax = (unsigned int*)ws;
    unsigned short* Q1 = (unsigned short*)(ws + 256);
    unsigned short* Q2 = Q1 + nW1;
    unsigned short* Xb = Q2 + nW2;
    unsigned short* H  = Xb + nX;

    init_amax<<<1, 64, 0, stream>>>(amax);
    absmax_kernel<<<1024, 256, 0, stream>>>((const float4*)W1, nW1 / 4, amax + 0);
    absmax_kernel<<<1024, 256, 0, stream>>>((const float4*)W2, nW2 / 4, amax + 1);
    quant_kernel<<<2048, 256, 0, stream>>>((const float4*)W1, nW1 / 4, amax + 0, (ushort4*)Q1);
    quant_kernel<<<2048, 256, 0, stream>>>((const float4*)W2, nW2 / 4, amax + 1, (ushort4*)Q2);
    cast_bf16_kernel<<<2048, 256, 0, stream>>>((const float4*)x, nX / 4, (ushort4*)Xb);

    // h = relu(scale1 * (x @ Q1^T) + b1) -> bf16
    gemm8<1><<<dim3((Dh / 256) * (Bm / 256)), 512, 0, stream>>>(
        Xb, Q1, b1, amax + 0, nullptr, H, Bm, Dh, Din, Dh / 256);
    // y = scale2 * (h @ Q2^T) + b2 -> f32
    gemm8<0><<<dim3((Dout / 256) * (Bm / 256)), 512, 0, stream>>>(
        H, Q2, b2, amax + 1, out, nullptr, Bm, Dout, Dh, Dout / 256);
}

// Round 9
// 534.165 us; speedup vs baseline: 2.4520x; 2.4520x over previous
//
#include <hip/hip_runtime.h>
#include <hip/hip_bf16.h>
#include <stdint.h>

typedef __attribute__((ext_vector_type(8))) short short8;
typedef __attribute__((ext_vector_type(4))) float f32x4;

#define AS1 __attribute__((address_space(1)))
#define AS3 __attribute__((address_space(3)))

// RNE float->bf16 (inputs are finite; no NaN handling needed)
static __device__ __forceinline__ unsigned short f2bf(float f) {
    unsigned int u = __float_as_uint(f);
    u += 0x7FFFu + ((u >> 16) & 1u);
    return (unsigned short)(u >> 16);
}

__global__ void init_amax(unsigned int* amax) {
    if (threadIdx.x < 2) amax[threadIdx.x] = 0u;
}

__global__ void absmax_kernel(const float4* __restrict__ w, size_t n4,
                              unsigned int* __restrict__ out) {
    float m = 0.0f;
    size_t i = (size_t)blockIdx.x * blockDim.x + threadIdx.x;
    size_t stride = (size_t)gridDim.x * blockDim.x;
    for (; i < n4; i += stride) {
        float4 v = w[i];
        m = fmaxf(m, fmaxf(fmaxf(fabsf(v.x), fabsf(v.y)),
                           fmaxf(fabsf(v.z), fabsf(v.w))));
    }
    #pragma unroll
    for (int off = 32; off > 0; off >>= 1)
        m = fmaxf(m, __shfl_down(m, off, 64));
    __shared__ float sm[4];
    int lane = threadIdx.x & 63, wid = threadIdx.x >> 6;
    if (lane == 0) sm[wid] = m;
    __syncthreads();
    if (threadIdx.x == 0) {
        float bm = fmaxf(fmaxf(sm[0], sm[1]), fmaxf(sm[2], sm[3]));
        atomicMax(out, __float_as_uint(bm));  // floats >=0: uint bit-compare monotone
    }
}

// FP4 E2M1 quantize to exact bf16 grid value (scale kept separate).
// idx = sum(a > mids[j]) matches np.searchsorted(mids, a, side='left').
static __device__ __forceinline__ unsigned short quant_one(float wv, float scale) {
    float a = fabsf(wv) / scale;
    int idx = (a > 0.25f) + (a > 0.75f) + (a > 1.25f) + (a > 1.75f)
            + (a > 2.5f)  + (a > 3.5f)  + (a > 5.0f);
    const unsigned long long lo = 0x3FC03F803F000000ull;  // bf16 bits {0,.5,1,1.5}
    const unsigned long long hi = 0x40C0408040404000ull;  // bf16 bits {2,3,4,6}
    unsigned long long tab = (idx < 4) ? lo : hi;
    unsigned short mag = (unsigned short)(tab >> ((idx & 3) * 16));
    unsigned short sgn = (unsigned short)((__float_as_uint(wv) >> 16) & 0x8000u);
    return (unsigned short)(mag | sgn);
}

__global__ void quant_kernel(const float4* __restrict__ w, size_t n4,
                             const unsigned int* __restrict__ amax,
                             ushort4* __restrict__ q) {
    const float scale = __uint_as_float(*amax) / 6.0f;
    size_t i = (size_t)blockIdx.x * blockDim.x + threadIdx.x;
    size_t stride = (size_t)gridDim.x * blockDim.x;
    for (; i < n4; i += stride) {
        float4 v = w[i];
        ushort4 o;
        o.x = quant_one(v.x, scale);
        o.y = quant_one(v.y, scale);
        o.z = quant_one(v.z, scale);
        o.w = quant_one(v.w, scale);
        q[i] = o;
    }
}

__global__ void cast_bf16_kernel(const float4* __restrict__ x, size_t n4,
                                 ushort4* __restrict__ o) {
    size_t i = (size_t)blockIdx.x * blockDim.x + threadIdx.x;
    size_t stride = (size_t)gridDim.x * blockDim.x;
    for (; i < n4; i += stride) {
        float4 v = x[i];
        ushort4 r;
        r.x = f2bf(v.x); r.y = f2bf(v.y); r.z = f2bf(v.z); r.w = f2bf(v.w);
        o[i] = r;
    }
}

// ========== 256x256 GEMM, BK=64, group-pipelined (R6 core, verified) ==========
// C[M][N] = A[M][K] (bf16) * B[N][K]^T (bf16), f32 acc.
// 512 thr = 8 waves (2M x 4N), per-wave 128x64, 2 K-tiles/iter.
// LDS 128KiB, buf by tile parity; per buf: A0@0 A1@16K B0@32K B1@48K.
// Subtile = 16 rows x 32 k (1024B); byte = swz(rin*64+kin*2), swz(x)=x^(((x>>9)&1)<<5).
// global_load_lds dest LINEAR; global source carries inverse swizzle.
//
// LAYA=1: A is the H'-BLOCKED internal layout (written by GEMM1's epilogue):
//   f(row,k) = (row>>4)*262144 + (k>>4)*512 + (row&3)*128 + ((row>>2)&3)*32 + (k&15)*2
// 16B of f = 8 consecutive k of one row -> drop-in for the A staging chunks.
// GEMM1 epilogue stores H' 128B-contiguous per instr (kills the 2x write amp
// seen as WRITE_SIZE 266MB for a 134MB H). GEMM2 (f32 out) epilogue goes via
// LDS (2 passes, 16B-block XOR swizzle) -> full-row 1KB coalesced stores.

#define GLL(gp, dst)                                                    \
    __builtin_amdgcn_global_load_lds((const AS1 unsigned int*)(gp),     \
        (AS3 unsigned int*)(dst), 16, 0, 0)

#define STGA(gp, ldsoff)                                        \
    do {                                                        \
        GLL((gp) + goffA0, lds + (ldsoff) + tid * 16);          \
        GLL((gp) + goffA1, lds + (ldsoff) + 8192 + tid * 16);   \
    } while (0)

#define STGB(gp, ldsoff)                                        \
    do {                                                        \
        GLL((gp) + goffB0, lds + (ldsoff) + tid * 16);          \
        GLL((gp) + goffB1, lds + (ldsoff) + 8192 + tid * 16);   \
    } while (0)

// byte advance for a k-offset of e ELEMENTS
#define KAB(e) ((size_t)(e) * (LAYA ? 32 : 2))
#define KBB(e) ((size_t)(e) * 2)

// 4 ds_read_b128: dst[i] = subtile (s0 + 2*i) of base
#define LD4(dst, base, s0)                                                    \
    do {                                                                      \
        _Pragma("unroll") for (int _i = 0; _i < 4; ++_i)                      \
            dst[_i] = *(const short8*)((base) + ((s0) + _i * 2) * 1024);      \
    } while (0)

// 16 MFMA: acc[AH*4 + i][j] += ARR[i] * BRR[j]
#define MFG(AH, ARR, BRR)                                                      \
    do {                                                                       \
        _Pragma("unroll") for (int _i = 0; _i < 4; ++_i)                       \
            _Pragma("unroll") for (int _j = 0; _j < 4; ++_j)                   \
                acc[(AH) * 4 + _i][_j] =                                       \
                    __builtin_amdgcn_mfma_f32_16x16x32_bf16(                   \
                        ARR[_i], BRR[_j], acc[(AH) * 4 + _i][_j], 0, 0, 0);    \
    } while (0)

#define BAR()  __builtin_amdgcn_s_barrier()
#define PRIO(x) __builtin_amdgcn_s_setprio(x)
#define SCHB() __builtin_amdgcn_sched_barrier(0)
#define LGKM(n) do { SCHB(); asm volatile("s_waitcnt lgkmcnt(" #n ")"); SCHB(); } while (0)

// One K-tile (R6-verified). VMODE: 2 = vmcnt(6), 1 = vmcnt(0), 0 = none.
#define KTILE(ldsB_, ldsA_, MA1, kA1, oA1, MORE, kNXT, oB0, oB1, oA0, VMODE)   \
    do {                                                                       \
        LD4(bE, ldsB_, 0);             /* B κ0: 4 reads */                     \
        LD4(aP, ldsA_, 0);             /* A h0 κ0: 4 */                        \
        LD4(aQ, ldsA_, 8);             /* A h1 κ0: 4 */                        \
        if (MA1) STGA(pA1 + KAB(kA1), oA1);                                    \
        LGKM(4);                       /* bE+aP ready, aQ in flight */         \
        PRIO(1); MFG(0, aP, bE); PRIO(0);                                      \
        LD4(bO, ldsB_, 1);             /* B κ1: 4 */                           \
        LD4(aP, ldsA_, 1);             /* A h0 κ1: 4 */                        \
        LGKM(8);                       /* aQ ready; bO,aP' in flight */        \
        PRIO(1); MFG(1, aQ, bE); PRIO(0);                                      \
        LD4(aQ, ldsA_, 9);             /* A h1 κ1: 4 */                        \
        LGKM(4);                       /* bO+aP' ready; aQ' in flight */       \
        PRIO(1); MFG(0, aP, bO); PRIO(0);                                      \
        LGKM(0);                       /* all 24 reads done -> buf free */     \
        BAR();                                                                 \
        if (MORE) { STGB(pB0 + KBB(kNXT), oB0); STGB(pB1 + KBB(kNXT), oB1);    \
                    STGA(pA0 + KAB(kNXT), oA0); }                              \
        SCHB();                                                                \
        PRIO(1); MFG(1, aQ, bO); PRIO(0);                                      \
        if (VMODE == 2) { asm volatile("s_waitcnt vmcnt(6)"); }                \
        if (VMODE == 1) { asm volatile("s_waitcnt vmcnt(0)"); }                \
        BAR();                                                                 \
    } while (0)

template <int RELU_BF16, int LAYA>
__global__ __launch_bounds__(512, 2)
void gemm8(const char* __restrict__ A,          // LAYA=0: row-major bf16; 1: H'-blocked
           const unsigned short* __restrict__ B,
           const float* __restrict__ bias,
           const unsigned int* __restrict__ amax,
           float* __restrict__ outF,            // RELU_BF16=0 dest (row-major f32)
           char* __restrict__ outH,             // RELU_BF16=1 dest (H'-blocked bf16)
           int M, int N, int K, int gx, int cw) {
    __shared__ __align__(16) char lds[131072];

    const int tid  = threadIdx.x;
    const int lane = tid & 63;
    const int wid  = tid >> 6;
    const int wm   = wid >> 2;   // 0..1: 128-row half
    const int wn   = wid & 3;    // 0..3: 64-col slice

    // 2D-chunked XCD mapping: XCD c gets a cw x (nc/cw) block-rect; bx fastest
    const int nwg = gridDim.x;
    const int wg  = blockIdx.x;
    const int c   = wg & 7;
    const int idx = wg >> 3;
    const int nc  = nwg >> 3;
    const int cxc = gx / cw;                 // chunks along x
    const int ox  = (c % cxc) * cw;
    const int oy  = (c / cxc) * (nc / cw);
    const int bx  = ox + idx % cw;
    const int by  = oy + idx / cw;
    const int col0 = bx * 256;
    const int row0 = by * 256;

    // per-lane swizzled ds_read byte offset within a 1024B subtile
    int sp = ((lane & 15) << 6) + ((lane >> 4) << 4);
    sp ^= ((sp >> 9) & 1) << 5;

    const char* ldsA_E = lds + wm * 16384 + sp;
    const char* ldsB_E = lds + 32768 + (wn >> 1) * 16384 + (wn & 1) * 8192 + sp;
    const char* ldsA_O = ldsA_E + 65536;
    const char* ldsB_O = ldsB_E + 65536;

    // stage source byte-offsets: LDS linear off o = l*8192 + tid*16 holds
    // element (row,k) = unswz(o); A offset per LAYA, B row-major.
    int goffA0, goffA1, goffB0, goffB1;
    {
        #pragma unroll
        for (int h = 0; h < 2; ++h) {
            int o = h * 8192 + tid * 16;
            int s = o >> 10, b = o & 1023;
            b ^= ((b >> 9) & 1) << 5;
            int row = ((s >> 1) << 4) + (b >> 6);
            int k   = ((s & 1) << 5) + ((b & 63) >> 1);
            int gB  = (row * K + k) * 2;
            int gA  = LAYA ? ((row >> 4) * 262144 + (k >> 4) * 512 +
                              (row & 3) * 128 + ((row >> 2) & 3) * 32 + (k & 15) * 2)
                           : gB;
            if (h == 0) { goffA0 = gA; goffB0 = gB; }
            else        { goffA1 = gA; goffB1 = gB; }
        }
    }
    const char* pA0 = A + (LAYA ? (size_t)row0 * 16384 : (size_t)row0 * K * 2);
    const char* pA1 = A + (LAYA ? (size_t)(row0 + 128) * 16384
                                : (size_t)(row0 + 128) * K * 2);
    const char* pB0 = (const char*)B + (size_t)col0 * K * 2;
    const char* pB1 = (const char*)B + (size_t)(col0 + 128) * K * 2;

    // prologue: tile0 [B0,B1,A0,A1] -> E; tile1 [B0,B1,A0] -> O
    STGB(pB0, 32768); STGB(pB1, 49152); STGA(pA0, 0); STGA(pA1, 16384);
    STGB(pB0 + KBB(64), 98304); STGB(pB1 + KBB(64), 114688);
    STGA(pA0 + KAB(64), 65536);
    asm volatile("s_waitcnt vmcnt(6)");   // tile0's 8 loads landed
    BAR();

    f32x4 acc[8][4] = {};
    short8 aP[4], aQ[4], bE[4], bO[4];
    const int NIT = K >> 7;

    for (int it = 0; it < NIT - 1; ++it) {
        const int o0 = it * 128;
        KTILE(ldsB_E, ldsA_E, 1, o0 + 64, 81920,
              1, o0 + 128, 32768, 49152, 0, 2);
        KTILE(ldsB_O, ldsA_O, 1, o0 + 128, 16384,
              1, o0 + 192, 98304, 114688, 65536, 2);
    }
    {
        const int o0 = (NIT - 1) * 128;   // peeled tail
        KTILE(ldsB_E, ldsA_E, 1, o0 + 64, 81920,
              0, 0, 0, 0, 0, 1);          // drain: vmcnt(0)
        KTILE(ldsB_O, ldsA_O, 0, 0, 0,
              0, 0, 0, 0, 0, 0);          // nothing outstanding
    }

    // acc C/D layout (verified m89/m91): col = lane&15, row = (lane>>4)*4 + r
    const float scale = __uint_as_float(*amax) / 6.0f;

    if (RELU_BF16) {
        // H'-blocked store: per (j,i,r) one 2B store, 64 lanes span 128B contiguous
        const int gbit = (lane >> 4) * 32 + (lane & 15) * 2;
        #pragma unroll
        for (int j = 0; j < 4; ++j) {
            const int col = col0 + wn * 64 + j * 16 + (lane & 15);
            const float bvv = bias[col];
            const size_t ktb = (size_t)((col0 >> 4) + wn * 4 + j) * 512;
            #pragma unroll
            for (int i = 0; i < 8; ++i) {
                const size_t rtb = (size_t)(((row0 + wm * 128) >> 4) + i) * 262144;
                #pragma unroll
                for (int r = 0; r < 4; ++r) {
                    float v = fmaxf(acc[i][j][r] * scale + bvv, 0.0f);
                    *(unsigned short*)(outH + rtb + ktb + r * 128 + gbit) = f2bf(v);
                }
            }
        }
    } else {
        // f32 out via LDS: 2 passes (wm groups); 16B-block XOR keyed on (row>>2)&3
        #pragma unroll
        for (int p = 0; p < 2; ++p) {
            if (wm == p) {
                #pragma unroll
                for (int j = 0; j < 4; ++j) {
                    const int colb = wn * 64 + j * 16 + (lane & 15);
                    const float bvv = bias[col0 + colb];
                    #pragma unroll
                    for (int i = 0; i < 8; ++i) {
                        #pragma unroll
                        for (int r = 0; r < 4; ++r) {
                            const int row_l = i * 16 + (lane >> 4) * 4 + r;
                            const int blk = (colb >> 2) ^ (((row_l >> 2) & 3) << 2);
                            *(float*)(lds + row_l * 1024 + blk * 16 + (colb & 3) * 4)
                                = acc[i][j][r] * scale + bvv;
                        }
                    }
                }
            }
            asm volatile("s_waitcnt lgkmcnt(0)");
            BAR();
            #pragma unroll
            for (int q = 0; q < 16; ++q) {
                const int flat  = q * 8192 + tid * 16;
                const int row_l = flat >> 10;
                const int blk0  = (flat >> 4) & 63;
                const int blk   = blk0 ^ (((row_l >> 2) & 3) << 2);
                f32x4 v = *(const f32x4*)(lds + row_l * 1024 + blk * 16);
                *(f32x4*)(outF + (size_t)(row0 + p * 128 + row_l) * N
                                 + col0 + blk0 * 4) = v;
            }
            BAR();
        }
    }
}

extern "C" void kernel_launch(void* const* d_in, const int* in_sizes, int n_in,
                              void* d_out, int out_size, void* d_ws, size_t ws_size,
                              hipStream_t stream) {
    const float* x  = (const float*)d_in[0];   // [8192, 2048]
    const float* W1 = (const float*)d_in[1];   // [8192, 2048]
    const float* b1 = (const float*)d_in[2];   // [8192]
    const float* W2 = (const float*)d_in[3];   // [2048, 8192]
    const float* b2 = (const float*)d_in[4];   // [2048]
    float* out = (float*)d_out;                // [8192, 2048] f32

    const int Bm = 8192, Din = 2048, Dh = 8192, Dout = 2048;
    const size_t nW1 = (size_t)Dh * Din;
    const size_t nW2 = (size_t)Dout * Dh;
    const size_t nX  = (size_t)Bm * Din;
    const size_t nH  = (size_t)Bm * Dh;

    const size_t need = 256 + 2 * (nW1 + nW2 + nX + nH);
    if (ws_size < need) return;

    uint8_t* ws = (uint8_t*)d_ws;
    unsigned int*   amax = (unsigned int*)ws;
    unsigned short* Q1 = (unsigned short*)(ws + 256);
    unsigned short* Q2 = Q1 + nW1;
    unsigned short* Xb = Q2 + nW2;
    char*           H  = (char*)(Xb + nX);     // H'-blocked bf16, nH*2 bytes

    init_amax<<<1, 64, 0, stream>>>(amax);
    absmax_kernel<<<1024, 256, 0, stream>>>((const float4*)W1, nW1 / 4, amax + 0);
    absmax_kernel<<<1024, 256, 0, stream>>>((const float4*)W2, nW2 / 4, amax + 1);
    quant_kernel<<<2048, 256, 0, stream>>>((const float4*)W1, nW1 / 4, amax + 0, (ushort4*)Q1);
    quant_kernel<<<2048, 256, 0, stream>>>((const float4*)W2, nW2 / 4, amax + 1, (ushort4*)Q2);
    cast_bf16_kernel<<<2048, 256, 0, stream>>>((const float4*)x, nX / 4, (ushort4*)Xb);

    // h = relu(scale1 * (x @ Q1^T) + b1) -> H' blocked bf16
    gemm8<1, 0><<<dim3((Dh / 256) * (Bm / 256)), 512, 0, stream>>>(
        (const char*)Xb, Q1, b1, amax + 0, nullptr, H,
        Bm, Dh, Din, /*gx=*/Dh / 256, /*cw=*/16);
    // y = scale2 * (h @ Q2^T) + b2 -> f32 row-major
    gemm8<0, 1><<<dim3((Dout / 256) * (Bm / 256)), 512, 0, stream>>>(
        H, Q2, b2, amax + 1, out, nullptr,
        Bm, Dout, Dh, /*gx=*/Dout / 256, /*cw=*/8);
}